// Round 1
// baseline (120.198 us; speedup 1.0000x reference)
//
#include <hip/hip_runtime.h>

// ROI align-style pooling (bilinear), matches reference _pool_one_roi exactly.
// img: (1,128,128,1024) f32, rois: (1,256,4) f32 (x,y,w,h in pixels)
// out: (1,256,7,7,1024) f32
//
// R6: strip-per-block (as R5) + explicit 1-deep register pipeline +
//     __launch_bounds__(256,4) to cap VGPR <= 128 (>=4 blocks/CU resident;
//     the full 28-load hoist in R5 likely pushed VGPR > 128 -> 2 waves/SIMD)
//     + nontemporal output stores (51 MB streamed once, zero reuse -> keep
//     it from evicting the image working set in L2/L3).

#define IMG_H 128
#define IMG_W 128
#define IMG_C 1024
#define POOLK 7
#define NROIS 256

typedef float vfloat4 __attribute__((ext_vector_type(4)));

__global__ __launch_bounds__(256, 4) void roi_pool_kernel(
    const float* __restrict__ img,
    const float* __restrict__ rois,
    float* __restrict__ out) {
  const int iy = blockIdx.x;   // 0..6
  const int r  = blockIdx.y;   // 0..255

  const vfloat4 roi = *(const vfloat4*)(rois + (size_t)r * 4);

  // c = (roi * SCALE).astype(int32): non-negative, trunc == floor.
  const int x0 = (int)(roi.x * 0.0625f);
  const int y0 = (int)(roi.y * 0.0625f);
  const int w  = (int)(roi.z * 0.0625f);
  const int h  = (int)(roi.w * 0.0625f);

  // y geometry fixed for the whole strip.
  const float sy = (float)iy * ((float)h * (1.0f / 7.0f));
  const float fy = floorf(sy);
  const float ty = sy - fy;
  const int y_lo = (int)fy;
  const int y_hi = min(y_lo + 1, max(h - 1, 0));
  const int gy0 = min(max(y0 + y_lo, 0), IMG_H - 1);
  const int gy1 = min(max(y0 + y_hi, 0), IMG_H - 1);

  const int c = threadIdx.x * 4;  // 256 threads x float4 = 1024 channels
  const float* row0 = img + (size_t)gy0 * (IMG_W * IMG_C) + c;
  const float* row1 = img + (size_t)gy1 * (IMG_W * IMG_C) + c;
  float* orow = out + (((size_t)r * POOLK + iy) * POOLK) * IMG_C + c;

  const float step_x = (float)w * (1.0f / 7.0f);
  const int xmax = max(w - 1, 0);

  // ---- software pipeline: corners for ix in flight while lerping ix-1 ----
  // ix = 0: sx = 0 -> fx = 0, tx = 0, x_lo = 0, x_hi = min(1, xmax).
  float tx_c = 0.0f;
  const int gx0_0 = min(max(x0, 0), IMG_W - 1);
  const int gx1_0 = min(max(x0 + min(1, xmax), 0), IMG_W - 1);
  vfloat4 v00 = *(const vfloat4*)(row0 + (size_t)gx0_0 * IMG_C);
  vfloat4 v01 = *(const vfloat4*)(row0 + (size_t)gx1_0 * IMG_C);
  vfloat4 v10 = *(const vfloat4*)(row1 + (size_t)gx0_0 * IMG_C);
  vfloat4 v11 = *(const vfloat4*)(row1 + (size_t)gx1_0 * IMG_C);

#pragma unroll
  for (int ix = 0; ix < POOLK; ++ix) {
    vfloat4 n00{}, n01{}, n10{}, n11{};
    float tx_n = 0.0f;
    if (ix + 1 < POOLK) {
      // geometry + prefetch for the NEXT ix (compile-time under full unroll)
      const float sx = (float)(ix + 1) * step_x;
      const float fx = floorf(sx);
      tx_n = sx - fx;
      const int x_lo = (int)fx;
      const int x_hi = min(x_lo + 1, xmax);
      const int gx0 = min(max(x0 + x_lo, 0), IMG_W - 1);
      const int gx1 = min(max(x0 + x_hi, 0), IMG_W - 1);
      n00 = *(const vfloat4*)(row0 + (size_t)gx0 * IMG_C);
      n01 = *(const vfloat4*)(row0 + (size_t)gx1 * IMG_C);
      n10 = *(const vfloat4*)(row1 + (size_t)gx0 * IMG_C);
      n11 = *(const vfloat4*)(row1 + (size_t)gx1 * IMG_C);
    }

    const vfloat4 top = v00 + tx_c * (v01 - v00);
    const vfloat4 bot = v10 + tx_c * (v11 - v10);
    const vfloat4 o   = top + ty * (bot - top);
    __builtin_nontemporal_store(o, (vfloat4*)(orow + (size_t)ix * IMG_C));

    v00 = n00; v01 = n01; v10 = n10; v11 = n11; tx_c = tx_n;
  }
}

extern "C" void kernel_launch(void* const* d_in, const int* in_sizes, int n_in,
                              void* d_out, int out_size, void* d_ws, size_t ws_size,
                              hipStream_t stream) {
  const float* img  = (const float*)d_in[0];   // 1*128*128*1024
  const float* rois = (const float*)d_in[1];   // 1*256*4
  float* out = (float*)d_out;                  // 1*256*7*7*1024

  dim3 grid(POOLK, NROIS);   // (iy, roi) strips
  dim3 block(256);
  roi_pool_kernel<<<grid, block, 0, stream>>>(img, rois, out);
}

// Round 2
// 119.086 us; speedup vs baseline: 1.0093x; 1.0093x over previous
//
#include <hip/hip_runtime.h>

// ROI align-style pooling (bilinear), matches reference _pool_one_roi exactly.
// img: (1,128,128,1024) f32, rois: (1,256,4) f32 (x,y,w,h in pixels)
// out: (1,256,7,7,1024) f32
//
// R7: occupancy + locality attack (kernel est. ~34us, private roofline ~18us,
//     stall = cache-cold scattered read latency at only 16 waves/CU):
//  - readfirstlane all block-uniform geometry -> SGPRs, scalar address math,
//    loads become saddr-form; live VGPR ~= 48.
//  - __launch_bounds__(256, 8): 64-VGPR cap -> 8 blocks/CU = 32 waves/CU
//    (2x TLP vs R6's cap of 4 blocks/CU) to cover L2/HBM miss latency.
//  - XCD-chunk swizzle: all 7 iy-strips of an ROI (plus 32 consecutive ROIs)
//    on ONE XCD -> adjacent strips share image rows in the same L2
//    (previously the 7 strips round-robined across all 8 XCDs).
//  - keep depth-1 register pipeline + nontemporal stores.

#define IMG_H 128
#define IMG_W 128
#define IMG_C 1024
#define POOLK 7
#define NROIS 256
#define NBLK (POOLK * NROIS)   // 1792
#define NXCD 8
#define CHUNK (NBLK / NXCD)    // 224  (1792 % 8 == 0 -> bijective swizzle)

typedef float vfloat4 __attribute__((ext_vector_type(4)));

__global__ __launch_bounds__(256, 8) void roi_pool_kernel(
    const float* __restrict__ img,
    const float* __restrict__ rois,
    float* __restrict__ out) {
  // XCD-chunk swizzle (round-robin hw assignment assumed: xcd = blockIdx % 8).
  const int orig = (int)blockIdx.x;
  const int newb = (orig & (NXCD - 1)) * CHUNK + (orig >> 3);
  const int r  = newb / POOLK;
  const int iy = newb - r * POOLK;

  // Block-uniform ROI geometry. rois address is uniform -> scalar load path.
  const vfloat4 roi = *(const vfloat4*)(rois + (size_t)r * 4);

  // c = (roi * SCALE).astype(int32): non-negative, trunc == floor.
  const int x0 = __builtin_amdgcn_readfirstlane((int)(roi.x * 0.0625f));
  const int y0 = __builtin_amdgcn_readfirstlane((int)(roi.y * 0.0625f));
  const int w  = __builtin_amdgcn_readfirstlane((int)(roi.z * 0.0625f));
  const int h  = __builtin_amdgcn_readfirstlane((int)(roi.w * 0.0625f));

  // y geometry fixed for the whole strip.
  const float sy = (float)iy * ((float)h * (1.0f / 7.0f));
  const float fy = floorf(sy);
  const float ty = sy - fy;
  const int y_lo = (int)fy;
  const int y_hi = min(y_lo + 1, max(h - 1, 0));
  const int gy0 = min(max(y0 + y_lo, 0), IMG_H - 1);
  const int gy1 = min(max(y0 + y_hi, 0), IMG_H - 1);

  // Uniform row element-offsets, pinned to SGPR.
  const int row0_e = __builtin_amdgcn_readfirstlane(gy0 * (IMG_W * IMG_C));
  const int row1_e = __builtin_amdgcn_readfirstlane(gy1 * (IMG_W * IMG_C));

  const int c = (int)threadIdx.x * 4;  // 256 threads x float4 = 1024 channels
  float* orow = out + (((size_t)r * POOLK + iy) * POOLK) * IMG_C + c;

  const float step_x = (float)w * (1.0f / 7.0f);
  const int xmax = max(w - 1, 0);

  // ---- depth-1 register pipeline over ix ----
  // ix = 0: sx = 0 -> tx = 0, x_lo = 0, x_hi = min(1, xmax).
  float tx_c = 0.0f;
  {
    const int gx0_0 = min(max(x0, 0), IMG_W - 1);
    const int gx1_0 = min(max(x0 + min(1, xmax), 0), IMG_W - 1);
    // fallthrough into pipeline registers below
    #define OFF(row_e, gx) ((size_t)__builtin_amdgcn_readfirstlane((row_e) + (gx) * IMG_C) + c)
    // (macro used consistently so every load is SGPR-base + lane offset)
    // initial corner loads:
    // declared after macro for scoping
    ;
    #undef OFF
  }
  const int gx0_0 = min(max(x0, 0), IMG_W - 1);
  const int gx1_0 = min(max(x0 + min(1, xmax), 0), IMG_W - 1);
  vfloat4 v00 = *(const vfloat4*)(img + (size_t)__builtin_amdgcn_readfirstlane(row0_e + gx0_0 * IMG_C) + c);
  vfloat4 v01 = *(const vfloat4*)(img + (size_t)__builtin_amdgcn_readfirstlane(row0_e + gx1_0 * IMG_C) + c);
  vfloat4 v10 = *(const vfloat4*)(img + (size_t)__builtin_amdgcn_readfirstlane(row1_e + gx0_0 * IMG_C) + c);
  vfloat4 v11 = *(const vfloat4*)(img + (size_t)__builtin_amdgcn_readfirstlane(row1_e + gx1_0 * IMG_C) + c);

#pragma unroll
  for (int ix = 0; ix < POOLK; ++ix) {
    vfloat4 n00{}, n01{}, n10{}, n11{};
    float tx_n = 0.0f;
    if (ix + 1 < POOLK) {
      // geometry + prefetch for the NEXT ix (compile-time under full unroll)
      const float sx = (float)(ix + 1) * step_x;
      const float fx = floorf(sx);
      tx_n = sx - fx;
      const int x_lo = (int)fx;
      const int x_hi = min(x_lo + 1, xmax);
      const int gx0 = min(max(x0 + x_lo, 0), IMG_W - 1);
      const int gx1 = min(max(x0 + x_hi, 0), IMG_W - 1);
      n00 = *(const vfloat4*)(img + (size_t)__builtin_amdgcn_readfirstlane(row0_e + gx0 * IMG_C) + c);
      n01 = *(const vfloat4*)(img + (size_t)__builtin_amdgcn_readfirstlane(row0_e + gx1 * IMG_C) + c);
      n10 = *(const vfloat4*)(img + (size_t)__builtin_amdgcn_readfirstlane(row1_e + gx0 * IMG_C) + c);
      n11 = *(const vfloat4*)(img + (size_t)__builtin_amdgcn_readfirstlane(row1_e + gx1 * IMG_C) + c);
    }

    const vfloat4 top = v00 + tx_c * (v01 - v00);
    const vfloat4 bot = v10 + tx_c * (v11 - v10);
    const vfloat4 o   = top + ty * (bot - top);
    __builtin_nontemporal_store(o, (vfloat4*)(orow + (size_t)ix * IMG_C));

    v00 = n00; v01 = n01; v10 = n10; v11 = n11; tx_c = tx_n;
  }
}

extern "C" void kernel_launch(void* const* d_in, const int* in_sizes, int n_in,
                              void* d_out, int out_size, void* d_ws, size_t ws_size,
                              hipStream_t stream) {
  const float* img  = (const float*)d_in[0];   // 1*128*128*1024
  const float* rois = (const float*)d_in[1];   // 1*256*4
  float* out = (float*)d_out;                  // 1*256*7*7*1024

  dim3 grid(NBLK);   // 1792 1-D, swizzled in-kernel
  dim3 block(256);
  roi_pool_kernel<<<grid, block, 0, stream>>>(img, rois, out);
}